// Round 3
// baseline (241.562 us; speedup 1.0000x reference)
//
#include <hip/hip_runtime.h>

typedef __attribute__((ext_vector_type(8))) short bf16x8;
typedef __attribute__((ext_vector_type(4))) float f32x4;

static __device__ __forceinline__ unsigned short f2bf(float f) {
    unsigned int u = __float_as_uint(f);
    u += 0x7fffu + ((u >> 16) & 1u);
    return (unsigned short)(u >> 16);
}
// round-half-up: P-values only (|rel err| <= 2^-9, tolerance-safe)
static __device__ __forceinline__ unsigned int pack2bf(float lo, float hi) {
    return ((__float_as_uint(lo) + 0x8000u) >> 16) |
           ((__float_as_uint(hi) + 0x8000u) & 0xffff0000u);
}
static __device__ __forceinline__ float bf2f(short v) {
    return __uint_as_float(((unsigned int)(unsigned short)v) << 16);
}
static __device__ __forceinline__ bf16x8 cvt8v(const float* p) {
    f32x4 a = *(const f32x4*)p, b = *(const f32x4*)(p + 4);
    bf16x8 r;
    r[0] = (short)f2bf(a[0]); r[1] = (short)f2bf(a[1]);
    r[2] = (short)f2bf(a[2]); r[3] = (short)f2bf(a[3]);
    r[4] = (short)f2bf(b[0]); r[5] = (short)f2bf(b[1]);
    r[6] = (short)f2bf(b[2]); r[7] = (short)f2bf(b[3]);
    return r;
}
static __device__ __forceinline__ bf16x8 scale8v(bf16x8 v, float s) {
    bf16x8 r;
    #pragma unroll
    for (int j = 0; j < 8; ++j) r[j] = (short)f2bf(bf2f(v[j]) * s);
    return r;
}
static __device__ __forceinline__ uint4 cvt8(const float* p) {
    bf16x8 r = cvt8v(p);
    union { bf16x8 v; uint4 u; } c; c.v = r; return c.u;
}
// async global->LDS, 16B/lane; LDS dest = wave-uniform base + lane*16
static __device__ __forceinline__ void glds16(const unsigned short* g, unsigned short* l) {
    __builtin_amdgcn_global_load_lds(
        (const __attribute__((address_space(1))) unsigned int*)g,
        (__attribute__((address_space(3))) unsigned int*)l, 16, 0, 0);
}

// ---------------------------------------------------------------------------
// Fused prep: cvt x -> x_bf, cvt k_g -> kg_bf, transpose+cvt W_qkv, W_out.
// grid 5120: [0,2048) x | [2048,4096) k_g | [4096,4864) Wqkv | [4864,5120) Wout
// ---------------------------------------------------------------------------
static __device__ __forceinline__ void transpose_tile(
    const float* __restrict__ src, unsigned short* __restrict__ dst,
    int R, int C, int bx, int by, int tid)
{
    __shared__ unsigned short t[64 * 72];
    const int r0 = by * 64, c0 = bx * 64;
    #pragma unroll
    for (int i = 0; i < 4; ++i) {
        int idx = tid + i * 256;
        int row = idx >> 4, seg = idx & 15;
        f32x4 v = *(const f32x4*)&src[(size_t)(r0 + row) * C + c0 + seg * 4];
        #pragma unroll
        for (int j = 0; j < 4; ++j) t[row * 72 + seg * 4 + j] = f2bf(v[j]);
    }
    __syncthreads();
    #pragma unroll
    for (int i = 0; i < 2; ++i) {
        int idx = tid + i * 256;
        int row = idx >> 3, seg = idx & 7;
        uint4 tv; unsigned short* tmp = (unsigned short*)&tv;
        #pragma unroll
        for (int j = 0; j < 8; ++j) tmp[j] = t[(seg * 8 + j) * 72 + row];
        *(uint4*)&dst[(size_t)(c0 + row) * R + r0 + seg * 8] = tv;
    }
}

__global__ __launch_bounds__(256) void prep_all(
    const float* __restrict__ x, unsigned short* __restrict__ x_bf,
    const float* __restrict__ kg, unsigned short* __restrict__ kg_bf,
    const float* __restrict__ Wq, unsigned short* __restrict__ wtq,
    const float* __restrict__ Wo, unsigned short* __restrict__ wto)
{
    const int t = blockIdx.x, tid = threadIdx.x;
    if (t < 2048) {
        size_t j = ((size_t)t * 256 + tid) * 8;
        *(uint4*)&x_bf[j] = cvt8(&x[j]);
    } else if (t < 4096) {
        size_t j = ((size_t)(t - 2048) * 256 + tid) * 8;
        *(uint4*)&kg_bf[j] = cvt8(&kg[j]);
    } else if (t < 4864) {
        int tt = t - 4096;               // W_qkv [1024][3072]: 48 col-tiles x 16
        transpose_tile(Wq, wtq, 1024, 3072, tt % 48, tt / 48, tid);
    } else {
        int tt = t - 4864;               // W_out [1024][1024]
        transpose_tile(Wo, wto, 1024, 1024, tt & 15, tt >> 4, tid);
    }
}

// ---------------------------------------------------------------------------
// gemm_qkv: qkv = x_bf @ wtq^T.  Q,K cols (bx<16) -> qk[4096][2048].
// V cols (bx>=16) -> written TRANSPOSED to vt[bh][hd=64][L=2048] via LDS.
// 128x128 tile, BK=32, glds16 staging (m97 pattern).
// ---------------------------------------------------------------------------
__global__ __launch_bounds__(256) void gemm_qkv(
    const unsigned short* __restrict__ A, const unsigned short* __restrict__ Bt,
    unsigned short* __restrict__ qk, unsigned short* __restrict__ vt)
{
    const int K = 1024;
    __shared__ unsigned short As[128 * 32];
    __shared__ unsigned short Bs[128 * 32];
    __shared__ unsigned short Tb[128 * 136];   // V-transpose scratch
    const int tid = threadIdx.x;
    const int wave = tid >> 6, lane = tid & 63, quad = lane >> 4, l16 = lane & 15;
    const int wr = (wave >> 1) * 64, wc = (wave & 1) * 64;
    const int m0 = blockIdx.y * 128, n0 = blockIdx.x * 128;

    const unsigned short* ga = A  + (size_t)(m0 + wave * 32 + (lane >> 2)) * K + (lane & 3) * 8;
    const unsigned short* gb = Bt + (size_t)(n0 + wave * 32 + (lane >> 2)) * K + (lane & 3) * 8;
    unsigned short* la = &As[wave * 32 * 32];
    unsigned short* lb = &Bs[wave * 32 * 32];
    const size_t step16 = (size_t)16 * K;

    f32x4 acc[4][4];
    #pragma unroll
    for (int i = 0; i < 4; ++i)
        #pragma unroll
        for (int j = 0; j < 4; ++j) acc[i][j] = (f32x4){0.f, 0.f, 0.f, 0.f};

    for (int kt = 0; kt < K; kt += 32) {
        glds16(ga, la); glds16(ga + step16, la + 512);
        glds16(gb, lb); glds16(gb + step16, lb + 512);
        ga += 32; gb += 32;
        __syncthreads();
        bf16x8 af[4], bf[4];
        #pragma unroll
        for (int i = 0; i < 4; ++i) {
            af[i] = *(const bf16x8*)&As[(wr + i * 16 + l16) * 32 + quad * 8];
            bf[i] = *(const bf16x8*)&Bs[(wc + i * 16 + l16) * 32 + quad * 8];
        }
        #pragma unroll
        for (int mi = 0; mi < 4; ++mi)
            #pragma unroll
            for (int ni = 0; ni < 4; ++ni)
                acc[mi][ni] = __builtin_amdgcn_mfma_f32_16x16x32_bf16(
                    af[mi], bf[ni], acc[mi][ni], 0, 0, 0);
        __syncthreads();
    }

    if (blockIdx.x < 16) {        // Q|K part: normal write, stride 2048
        #pragma unroll
        for (int mi = 0; mi < 4; ++mi)
            #pragma unroll
            for (int ni = 0; ni < 4; ++ni)
                #pragma unroll
                for (int r = 0; r < 4; ++r) {
                    int row = m0 + wr + mi * 16 + quad * 4 + r;
                    int col = n0 + wc + ni * 16 + l16;
                    qk[(size_t)row * 2048 + col] = f2bf(acc[mi][ni][r]);
                }
    } else {                      // V part: transpose via LDS -> vt[bh][hd][L]
        __syncthreads();
        #pragma unroll
        for (int mi = 0; mi < 4; ++mi)
            #pragma unroll
            for (int ni = 0; ni < 4; ++ni)
                #pragma unroll
                for (int r = 0; r < 4; ++r) {
                    int col = wc + ni * 16 + l16;            // hd-ish (0..127)
                    int row = wr + mi * 16 + quad * 4 + r;   // pos (0..127)
                    Tb[col * 136 + row] = f2bf(acc[mi][ni][r]);
                }
        __syncthreads();
        const int col = tid >> 1, r0 = (tid & 1) * 64;
        const int bh = (m0 >> 11) * 16 + ((int)blockIdx.x - 16) * 2 + (col >> 6);
        size_t base = ((size_t)bh * 64 + (col & 63)) * 2048 + (m0 & 2047) + r0;
        #pragma unroll
        for (int k = 0; k < 8; ++k)
            *(uint4*)&vt[base + k * 8] = *(const uint4*)&Tb[col * 136 + r0 + k * 8];
    }
}

// ---------------------------------------------------------------------------
// gemm2: out = y_ws @ wto^T, f32 out.  128(M) x 64(N) tile -> 512 blocks, 2/CU.
// 4 waves: 2x2, each 64x32.
// ---------------------------------------------------------------------------
__global__ __launch_bounds__(256) void gemm_n64(
    const unsigned short* __restrict__ A, const unsigned short* __restrict__ Bt,
    float* __restrict__ C)
{
    const int K = 1024, N = 1024;
    __shared__ unsigned short As[128 * 32];
    __shared__ unsigned short Bs[64 * 32];
    const int tid = threadIdx.x;
    const int wave = tid >> 6, lane = tid & 63, quad = lane >> 4, l16 = lane & 15;
    const int wr = (wave >> 1) * 64, wc = (wave & 1) * 32;
    const int m0 = blockIdx.y * 128, n0 = blockIdx.x * 64;

    const unsigned short* ga = A  + (size_t)(m0 + wave * 32 + (lane >> 2)) * K + (lane & 3) * 8;
    const unsigned short* gb = Bt + (size_t)(n0 + wave * 16 + (lane >> 2)) * K + (lane & 3) * 8;
    unsigned short* la = &As[wave * 32 * 32];
    unsigned short* lb = &Bs[wave * 16 * 32];
    const size_t step16 = (size_t)16 * K;

    f32x4 acc[4][2];
    #pragma unroll
    for (int i = 0; i < 4; ++i)
        #pragma unroll
        for (int j = 0; j < 2; ++j) acc[i][j] = (f32x4){0.f, 0.f, 0.f, 0.f};

    for (int kt = 0; kt < K; kt += 32) {
        glds16(ga, la); glds16(ga + step16, la + 512);
        glds16(gb, lb);
        ga += 32; gb += 32;
        __syncthreads();
        bf16x8 af[4], bf[2];
        #pragma unroll
        for (int i = 0; i < 4; ++i)
            af[i] = *(const bf16x8*)&As[(wr + i * 16 + l16) * 32 + quad * 8];
        #pragma unroll
        for (int i = 0; i < 2; ++i)
            bf[i] = *(const bf16x8*)&Bs[(wc + i * 16 + l16) * 32 + quad * 8];
        #pragma unroll
        for (int mi = 0; mi < 4; ++mi)
            #pragma unroll
            for (int ni = 0; ni < 2; ++ni)
                acc[mi][ni] = __builtin_amdgcn_mfma_f32_16x16x32_bf16(
                    af[mi], bf[ni], acc[mi][ni], 0, 0, 0);
        __syncthreads();
    }
    #pragma unroll
    for (int mi = 0; mi < 4; ++mi)
        #pragma unroll
        for (int ni = 0; ni < 2; ++ni)
            #pragma unroll
            for (int r = 0; r < 4; ++r) {
                int row = m0 + wr + mi * 16 + quad * 4 + r;
                int col = n0 + wc + ni * 16 + l16;
                C[(size_t)row * N + col] = acc[mi][ni][r];
            }
}

// ---------------------------------------------------------------------------
// attn9: dual-score causal flash attention.
// 64-row q-tiles, 128-thread blocks (2 waves x 32 q-rows), 64-key k-tiles.
// LDS = K 8K + G 8K + V 8K + P 8K = 32 KiB -> 5 blocks/CU (10 waves/CU),
// grid 1024 blocks heavy-first: attn7's occupancy/balance with attn8's
// 32-rows/wave LDS amortization (28 b128 reads serve 32 q-rows, was 26/16).
// ---------------------------------------------------------------------------
template<bool DIAG>
static __device__ __forceinline__ void attn_tile(
    const unsigned short* __restrict__ Kc, const unsigned short* __restrict__ Gc,
    const unsigned short* __restrict__ Vc, unsigned short* __restrict__ Pw,
    const bf16x8 (&qf)[2][2], const bf16x8 (&gf)[2][2],
    f32x4 (&o)[2][4], float (&lsum)[2],
    int rb, int swz0, int swz1, int pxr, int quad, int l16, int wave)
{
    // P store helper: [32 q][64 k] bf16, 8B chunks XOR-swizzled by row&7
    auto pstore = [&](int qj, int ni, unsigned long long v) {
        *(unsigned long long*)&Pw[(qj * 16 + l16) * 64 + (quad & 1) * 4 +
                                  (((ni * 2 + (quad >> 1)) ^ pxr) * 8)] = v;
    };

    #pragma unroll
    for (int ni = 0; ni < 4; ++ni) {
        const int kbase = ni * 16;                            // key rel q-tile base
        if (DIAG && kbase > wave * 32 + 31) {                 // both qj fully masked
            pstore(0, ni, 0ull); pstore(1, ni, 0ull);
            continue;
        }
        bf16x8 kf0 = *(const bf16x8*)((const char*)Kc + rb + swz0 + ni * 2048);
        bf16x8 kf1 = *(const bf16x8*)((const char*)Kc + rb + swz1 + ni * 2048);
        bf16x8 gb0 = *(const bf16x8*)((const char*)Gc + rb + swz0 + ni * 2048);
        bf16x8 gb1 = *(const bf16x8*)((const char*)Gc + rb + swz1 + ni * 2048);
        #pragma unroll
        for (int qj = 0; qj < 2; ++qj) {
            const int qtop = wave * 32 + qj * 16;
            if (DIAG && kbase > qtop + 15) {                  // this qj fully masked
                pstore(qj, ni, 0ull);
                continue;
            }
            f32x4 a = (f32x4){0.f, 0.f, 0.f, 0.f};
            a = __builtin_amdgcn_mfma_f32_16x16x32_bf16(kf0, qf[qj][0], a, 0, 0, 0);
            a = __builtin_amdgcn_mfma_f32_16x16x32_bf16(gb0, gf[qj][0], a, 0, 0, 0);
            a = __builtin_amdgcn_mfma_f32_16x16x32_bf16(kf1, qf[qj][1], a, 0, 0, 0);
            a = __builtin_amdgcn_mfma_f32_16x16x32_bf16(gb1, gf[qj][1], a, 0, 0, 0);
            float e0, e1, e2, e3;
            if (DIAG && (kbase + 15 > qtop)) {                // partial: per-elem mask
                const int qr = qtop + l16, kb = kbase + quad * 4;
                e0 = (kb + 0 <= qr) ? exp2f(a[0]) : 0.f;
                e1 = (kb + 1 <= qr) ? exp2f(a[1]) : 0.f;
                e2 = (kb + 2 <= qr) ? exp2f(a[2]) : 0.f;
                e3 = (kb + 3 <= qr) ? exp2f(a[3]) : 0.f;
            } else {
                e0 = exp2f(a[0]); e1 = exp2f(a[1]);
                e2 = exp2f(a[2]); e3 = exp2f(a[3]);
            }
            lsum[qj] += (e0 + e1) + (e2 + e3);
            unsigned int p01 = pack2bf(e0, e1), p23 = pack2bf(e2, e3);
            pstore(qj, ni, ((unsigned long long)p23 << 32) | p01);
        }
    }

    // V fragment prefetch overlaps the QK/exp phase (before the P-wait)
    bf16x8 vf[4][2];
    #pragma unroll
    for (int nd = 0; nd < 4; ++nd) {
        vf[nd][0] = *(const bf16x8*)((const char*)Vc + rb + swz0 + nd * 2048);
        vf[nd][1] = *(const bf16x8*)((const char*)Vc + rb + swz1 + nd * 2048);
    }
    asm volatile("s_waitcnt lgkmcnt(0)" ::: "memory");

    bf16x8 pa[2][2];
    #pragma unroll
    for (int qj = 0; qj < 2; ++qj)
        #pragma unroll
        for (int c = 0; c < 2; ++c)
            pa[qj][c] = *(const bf16x8*)&Pw[(qj * 16 + l16) * 64 +
                                            (((c * 4 + quad) ^ pxr) * 8)];
    #pragma unroll
    for (int nd = 0; nd < 4; ++nd) {
        o[0][nd] = __builtin_amdgcn_mfma_f32_16x16x32_bf16(pa[0][0], vf[nd][0], o[0][nd], 0, 0, 0);
        o[0][nd] = __builtin_amdgcn_mfma_f32_16x16x32_bf16(pa[0][1], vf[nd][1], o[0][nd], 0, 0, 0);
        o[1][nd] = __builtin_amdgcn_mfma_f32_16x16x32_bf16(pa[1][0], vf[nd][0], o[1][nd], 0, 0, 0);
        o[1][nd] = __builtin_amdgcn_mfma_f32_16x16x32_bf16(pa[1][1], vf[nd][1], o[1][nd], 0, 0, 0);
    }
}

__global__ __launch_bounds__(128, 3) void attn9(
    const unsigned short* __restrict__ qk, const float* __restrict__ qg,
    const unsigned short* __restrict__ kgb, const unsigned short* __restrict__ vt,
    unsigned short* __restrict__ y)
{
    const int L = 2048, DS = 2048, Dm = 1024;
    const float SC2 = 0.125f * 1.44269504088896f / 7.6246189861593985f;

    const int qt = 31 - (int)blockIdx.y;   // heavy tiles dispatch first
    const int bh = blockIdx.x, b = bh >> 4, h = bh & 15;
    const int tid = threadIdx.x, wave = tid >> 6, lane = tid & 63;
    const int quad = lane >> 4, l16 = lane & 15;

    __shared__ unsigned short K_l[4096];     // [64 key][64 hd] swizzled
    __shared__ unsigned short G_l[4096];
    __shared__ unsigned short V_l[4096];     // [hd][key] swizzled
    __shared__ unsigned short P_l[4096];     // per-wave [32][64] swizzled
    unsigned short* Pw = &P_l[wave * 2048];

    // Q fragments: 32 rows per wave = 2 x 16-row fragments
    bf16x8 qf[2][2], gf[2][2];
    const int qrow0 = qt * 64 + wave * 32;
    #pragma unroll
    for (int qj = 0; qj < 2; ++qj) {
        const unsigned short* qp = qk + (size_t)(b * L + qrow0 + qj * 16 + l16) * DS + h * 64;
        const float* gp = qg + (size_t)(b * L + qrow0 + qj * 16 + l16) * Dm + h * 64;
        #pragma unroll
        for (int c = 0; c < 2; ++c) {
            qf[qj][c] = scale8v(*(const bf16x8*)(qp + c * 32 + quad * 8), SC2);
            gf[qj][c] = scale8v(cvt8v(gp + c * 32 + quad * 8), SC2);
        }
    }

    f32x4 o[2][4];
    #pragma unroll
    for (int qj = 0; qj < 2; ++qj)
        #pragma unroll
        for (int nd = 0; nd < 4; ++nd) o[qj][nd] = (f32x4){0.f, 0.f, 0.f, 0.f};
    float lsum[2] = {0.f, 0.f};

    // staging: 2 waves, each covers 32 rows (4 x 8-row glds per array)
    const int srow = wave * 32 + (lane >> 3);
    const int c8 = (((lane & 7) ^ (lane >> 3)) & 7) * 8;
    const unsigned short* pk = qk + (size_t)(b * L + srow) * DS + 1024 + h * 64 + c8;
    const unsigned short* pg = kgb + (size_t)(b * L + srow) * Dm + h * 64 + c8;
    const unsigned short* pv = vt + ((size_t)bh * 64 + srow) * L + c8;
    unsigned short* lK = &K_l[wave * 2048];
    unsigned short* lG = &G_l[wave * 2048];
    unsigned short* lV = &V_l[wave * 2048];

    const int rb = l16 * 128;
    const int swz0 = ((quad     ^ (l16 & 7)) * 16);
    const int swz1 = (((4 + quad) ^ (l16 & 7)) * 16);
    const int pxr = l16 & 7;

    for (int kt = 0; kt < qt; ++kt) {
        __syncthreads();
        glds16(pk, lK); glds16(pk +  8 * DS, lK + 512);
        glds16(pk + 16 * DS, lK + 1024); glds16(pk + 24 * DS, lK + 1536);
        glds16(pg, lG); glds16(pg +  8 * Dm, lG + 512);
        glds16(pg + 16 * Dm, lG + 1024); glds16(pg + 24 * Dm, lG + 1536);
        glds16(pv, lV); glds16(pv +  8 * L,  lV + 512);
        glds16(pv + 16 * L, lV + 1024); glds16(pv + 24 * L, lV + 1536);
        pk += 64 * DS; pg += 64 * Dm; pv += 64;
        __syncthreads();
        attn_tile<false>(K_l, G_l, V_l, Pw, qf, gf, o, lsum,
                         rb, swz0, swz1, pxr, quad, l16, wave);
    }

    // ---- diagonal tile kt == qt ----
    {
        __syncthreads();
        glds16(pk, lK); glds16(pk +  8 * DS, lK + 512);
        glds16(pk + 16 * DS, lK + 1024); glds16(pk + 24 * DS, lK + 1536);
        glds16(pg, lG); glds16(pg +  8 * Dm, lG + 512);
        glds16(pg + 16 * Dm, lG + 1024); glds16(pg + 24 * Dm, lG + 1536);
        glds16(pv, lV); glds16(pv +  8 * L,  lV + 512);
        glds16(pv + 16 * L, lV + 1024); glds16(pv + 24 * L, lV + 1536);
        __syncthreads();
        attn_tile<true>(K_l, G_l, V_l, Pw, qf, gf, o, lsum,
                        rb, swz0, swz1, pxr, quad, l16, wave);
    }

    // normalize + write
    #pragma unroll
    for (int qj = 0; qj < 2; ++qj) {
        float rs = lsum[qj];
        rs += __shfl_xor(rs, 16);
        rs += __shfl_xor(rs, 32);
        #pragma unroll
        for (int r = 0; r < 4; ++r) {
            float inv = 1.f / __shfl(rs, (lane & 48) | (quad * 4 + r));
            int row = qt * 64 + wave * 32 + qj * 16 + quad * 4 + r;
            #pragma unroll
            for (int nd = 0; nd < 4; ++nd)
                y[(size_t)(b * L + row) * Dm + h * 64 + nd * 16 + l16] =
                    f2bf(o[qj][nd][r] * inv);
        }
    }
}

// ---------------------------------------------------------------------------
extern "C" void kernel_launch(void* const* d_in, const int* in_sizes, int n_in,
                              void* d_out, int out_size, void* d_ws, size_t ws_size,
                              hipStream_t stream) {
    const float* x     = (const float*)d_in[0];
    const float* q_g   = (const float*)d_in[1];
    const float* k_g   = (const float*)d_in[2];
    const float* W_qkv = (const float*)d_in[3];
    const float* W_out = (const float*)d_in[4];
    float* out = (float*)d_out;
    unsigned short* ws = (unsigned short*)d_ws;

    unsigned short* qk_ws = ws;                  // [4096][2048]  Q|K
    unsigned short* y_ws  = ws + 8388608;        // [4096][1024]
    unsigned short* wtq   = ws + 12582912;       // [3072][1024]
    unsigned short* wto   = ws + 15728640;       // [1024][1024]
    unsigned short* kg_bf = ws + 16777216;       // [4096][1024]
    unsigned short* x_bf  = ws + 20971520;       // [4096][1024]
    unsigned short* vt_bf = ws + 25165824;       // [32][64][2048]

    dim3 blk(256);
    prep_all<<<5120, blk, 0, stream>>>(x, x_bf, k_g, kg_bf, W_qkv, wtq, W_out, wto);
    gemm_qkv<<<dim3(24, 32), blk, 0, stream>>>(x_bf, wtq, qk_ws, vt_bf);
    attn9<<<dim3(32, 32), dim3(128), 0, stream>>>(qk_ws, q_g, kg_bf, vt_bf, y_ws);
    gemm_n64<<<dim3(16, 32), blk, 0, stream>>>(y_ws, wto, out);
}

// Round 4
// 236.731 us; speedup vs baseline: 1.0204x; 1.0204x over previous
//
#include <hip/hip_runtime.h>

typedef __attribute__((ext_vector_type(8))) short bf16x8;
typedef __attribute__((ext_vector_type(4))) float f32x4;

static __device__ __forceinline__ unsigned short f2bf(float f) {
    unsigned int u = __float_as_uint(f);
    u += 0x7fffu + ((u >> 16) & 1u);
    return (unsigned short)(u >> 16);
}
// round-half-up: P-values only (|rel err| <= 2^-9, tolerance-safe)
static __device__ __forceinline__ unsigned int pack2bf(float lo, float hi) {
    return ((__float_as_uint(lo) + 0x8000u) >> 16) |
           ((__float_as_uint(hi) + 0x8000u) & 0xffff0000u);
}
static __device__ __forceinline__ float bf2f(short v) {
    return __uint_as_float(((unsigned int)(unsigned short)v) << 16);
}
static __device__ __forceinline__ bf16x8 cvt8v(const float* p) {
    f32x4 a = *(const f32x4*)p, b = *(const f32x4*)(p + 4);
    bf16x8 r;
    r[0] = (short)f2bf(a[0]); r[1] = (short)f2bf(a[1]);
    r[2] = (short)f2bf(a[2]); r[3] = (short)f2bf(a[3]);
    r[4] = (short)f2bf(b[0]); r[5] = (short)f2bf(b[1]);
    r[6] = (short)f2bf(b[2]); r[7] = (short)f2bf(b[3]);
    return r;
}
static __device__ __forceinline__ bf16x8 scale8v(bf16x8 v, float s) {
    bf16x8 r;
    #pragma unroll
    for (int j = 0; j < 8; ++j) r[j] = (short)f2bf(bf2f(v[j]) * s);
    return r;
}
static __device__ __forceinline__ uint4 cvt8(const float* p) {
    bf16x8 r = cvt8v(p);
    union { bf16x8 v; uint4 u; } c; c.v = r; return c.u;
}
// async global->LDS, 16B/lane; LDS dest = wave-uniform base + lane*16
static __device__ __forceinline__ void glds16(const unsigned short* g, unsigned short* l) {
    __builtin_amdgcn_global_load_lds(
        (const __attribute__((address_space(1))) unsigned int*)g,
        (__attribute__((address_space(3))) unsigned int*)l, 16, 0, 0);
}

// ---------------------------------------------------------------------------
// Fused prep: cvt x -> x_bf, cvt k_g -> kg_bf, transpose+cvt W_qkv, W_out.
// grid 5120: [0,2048) x | [2048,4096) k_g | [4096,4864) Wqkv | [4864,5120) Wout
// ---------------------------------------------------------------------------
static __device__ __forceinline__ void transpose_tile(
    const float* __restrict__ src, unsigned short* __restrict__ dst,
    int R, int C, int bx, int by, int tid)
{
    __shared__ unsigned short t[64 * 72];
    const int r0 = by * 64, c0 = bx * 64;
    #pragma unroll
    for (int i = 0; i < 4; ++i) {
        int idx = tid + i * 256;
        int row = idx >> 4, seg = idx & 15;
        f32x4 v = *(const f32x4*)&src[(size_t)(r0 + row) * C + c0 + seg * 4];
        #pragma unroll
        for (int j = 0; j < 4; ++j) t[row * 72 + seg * 4 + j] = f2bf(v[j]);
    }
    __syncthreads();
    #pragma unroll
    for (int i = 0; i < 2; ++i) {
        int idx = tid + i * 256;
        int row = idx >> 3, seg = idx & 7;
        uint4 tv; unsigned short* tmp = (unsigned short*)&tv;
        #pragma unroll
        for (int j = 0; j < 8; ++j) tmp[j] = t[(seg * 8 + j) * 72 + row];
        *(uint4*)&dst[(size_t)(c0 + row) * R + r0 + seg * 8] = tv;
    }
}

__global__ __launch_bounds__(256) void prep_all(
    const float* __restrict__ x, unsigned short* __restrict__ x_bf,
    const float* __restrict__ kg, unsigned short* __restrict__ kg_bf,
    const float* __restrict__ Wq, unsigned short* __restrict__ wtq,
    const float* __restrict__ Wo, unsigned short* __restrict__ wto)
{
    const int t = blockIdx.x, tid = threadIdx.x;
    if (t < 2048) {
        size_t j = ((size_t)t * 256 + tid) * 8;
        *(uint4*)&x_bf[j] = cvt8(&x[j]);
    } else if (t < 4096) {
        size_t j = ((size_t)(t - 2048) * 256 + tid) * 8;
        *(uint4*)&kg_bf[j] = cvt8(&kg[j]);
    } else if (t < 4864) {
        int tt = t - 4096;               // W_qkv [1024][3072]: 48 col-tiles x 16
        transpose_tile(Wq, wtq, 1024, 3072, tt % 48, tt / 48, tid);
    } else {
        int tt = t - 4864;               // W_out [1024][1024]
        transpose_tile(Wo, wto, 1024, 1024, tt & 15, tt >> 4, tid);
    }
}

// ---------------------------------------------------------------------------
// gemm_qkv: qkv = x_bf @ wtq^T.  Q,K cols (bx<16) -> qk[4096][2048].
// V cols (bx>=16) -> written TRANSPOSED to vt[bh][hd=64][L=2048] via LDS.
// 128x128 tile, BK=32, glds16 staging (m97 pattern).
// ---------------------------------------------------------------------------
__global__ __launch_bounds__(256) void gemm_qkv(
    const unsigned short* __restrict__ A, const unsigned short* __restrict__ Bt,
    unsigned short* __restrict__ qk, unsigned short* __restrict__ vt)
{
    const int K = 1024;
    __shared__ unsigned short As[128 * 32];
    __shared__ unsigned short Bs[128 * 32];
    __shared__ unsigned short Tb[128 * 136];   // V-transpose scratch
    const int tid = threadIdx.x;
    const int wave = tid >> 6, lane = tid & 63, quad = lane >> 4, l16 = lane & 15;
    const int wr = (wave >> 1) * 64, wc = (wave & 1) * 64;
    const int m0 = blockIdx.y * 128, n0 = blockIdx.x * 128;

    const unsigned short* ga = A  + (size_t)(m0 + wave * 32 + (lane >> 2)) * K + (lane & 3) * 8;
    const unsigned short* gb = Bt + (size_t)(n0 + wave * 32 + (lane >> 2)) * K + (lane & 3) * 8;
    unsigned short* la = &As[wave * 32 * 32];
    unsigned short* lb = &Bs[wave * 32 * 32];
    const size_t step16 = (size_t)16 * K;

    f32x4 acc[4][4];
    #pragma unroll
    for (int i = 0; i < 4; ++i)
        #pragma unroll
        for (int j = 0; j < 4; ++j) acc[i][j] = (f32x4){0.f, 0.f, 0.f, 0.f};

    for (int kt = 0; kt < K; kt += 32) {
        glds16(ga, la); glds16(ga + step16, la + 512);
        glds16(gb, lb); glds16(gb + step16, lb + 512);
        ga += 32; gb += 32;
        __syncthreads();
        bf16x8 af[4], bf[4];
        #pragma unroll
        for (int i = 0; i < 4; ++i) {
            af[i] = *(const bf16x8*)&As[(wr + i * 16 + l16) * 32 + quad * 8];
            bf[i] = *(const bf16x8*)&Bs[(wc + i * 16 + l16) * 32 + quad * 8];
        }
        #pragma unroll
        for (int mi = 0; mi < 4; ++mi)
            #pragma unroll
            for (int ni = 0; ni < 4; ++ni)
                acc[mi][ni] = __builtin_amdgcn_mfma_f32_16x16x32_bf16(
                    af[mi], bf[ni], acc[mi][ni], 0, 0, 0);
        __syncthreads();
    }

    if (blockIdx.x < 16) {        // Q|K part: normal write, stride 2048
        #pragma unroll
        for (int mi = 0; mi < 4; ++mi)
            #pragma unroll
            for (int ni = 0; ni < 4; ++ni)
                #pragma unroll
                for (int r = 0; r < 4; ++r) {
                    int row = m0 + wr + mi * 16 + quad * 4 + r;
                    int col = n0 + wc + ni * 16 + l16;
                    qk[(size_t)row * 2048 + col] = f2bf(acc[mi][ni][r]);
                }
    } else {                      // V part: transpose via LDS -> vt[bh][hd][L]
        __syncthreads();
        #pragma unroll
        for (int mi = 0; mi < 4; ++mi)
            #pragma unroll
            for (int ni = 0; ni < 4; ++ni)
                #pragma unroll
                for (int r = 0; r < 4; ++r) {
                    int col = wc + ni * 16 + l16;            // hd-ish (0..127)
                    int row = wr + mi * 16 + quad * 4 + r;   // pos (0..127)
                    Tb[col * 136 + row] = f2bf(acc[mi][ni][r]);
                }
        __syncthreads();
        const int col = tid >> 1, r0 = (tid & 1) * 64;
        const int bh = (m0 >> 11) * 16 + ((int)blockIdx.x - 16) * 2 + (col >> 6);
        size_t base = ((size_t)bh * 64 + (col & 63)) * 2048 + (m0 & 2047) + r0;
        #pragma unroll
        for (int k = 0; k < 8; ++k)
            *(uint4*)&vt[base + k * 8] = *(const uint4*)&Tb[col * 136 + r0 + k * 8];
    }
}

// ---------------------------------------------------------------------------
// gemm2: out = y_ws @ wto^T, f32 out.  128(M) x 64(N) tile -> 512 blocks, 2/CU.
// 4 waves: 2x2, each 64x32.
// ---------------------------------------------------------------------------
__global__ __launch_bounds__(256) void gemm_n64(
    const unsigned short* __restrict__ A, const unsigned short* __restrict__ Bt,
    float* __restrict__ C)
{
    const int K = 1024, N = 1024;
    __shared__ unsigned short As[128 * 32];
    __shared__ unsigned short Bs[64 * 32];
    const int tid = threadIdx.x;
    const int wave = tid >> 6, lane = tid & 63, quad = lane >> 4, l16 = lane & 15;
    const int wr = (wave >> 1) * 64, wc = (wave & 1) * 32;
    const int m0 = blockIdx.y * 128, n0 = blockIdx.x * 64;

    const unsigned short* ga = A  + (size_t)(m0 + wave * 32 + (lane >> 2)) * K + (lane & 3) * 8;
    const unsigned short* gb = Bt + (size_t)(n0 + wave * 16 + (lane >> 2)) * K + (lane & 3) * 8;
    unsigned short* la = &As[wave * 32 * 32];
    unsigned short* lb = &Bs[wave * 16 * 32];
    const size_t step16 = (size_t)16 * K;

    f32x4 acc[4][2];
    #pragma unroll
    for (int i = 0; i < 4; ++i)
        #pragma unroll
        for (int j = 0; j < 2; ++j) acc[i][j] = (f32x4){0.f, 0.f, 0.f, 0.f};

    for (int kt = 0; kt < K; kt += 32) {
        glds16(ga, la); glds16(ga + step16, la + 512);
        glds16(gb, lb);
        ga += 32; gb += 32;
        __syncthreads();
        bf16x8 af[4], bf[2];
        #pragma unroll
        for (int i = 0; i < 4; ++i)
            af[i] = *(const bf16x8*)&As[(wr + i * 16 + l16) * 32 + quad * 8];
        #pragma unroll
        for (int i = 0; i < 2; ++i)
            bf[i] = *(const bf16x8*)&Bs[(wc + i * 16 + l16) * 32 + quad * 8];
        #pragma unroll
        for (int mi = 0; mi < 4; ++mi)
            #pragma unroll
            for (int ni = 0; ni < 2; ++ni)
                acc[mi][ni] = __builtin_amdgcn_mfma_f32_16x16x32_bf16(
                    af[mi], bf[ni], acc[mi][ni], 0, 0, 0);
        __syncthreads();
    }
    #pragma unroll
    for (int mi = 0; mi < 4; ++mi)
        #pragma unroll
        for (int ni = 0; ni < 2; ++ni)
            #pragma unroll
            for (int r = 0; r < 4; ++r) {
                int row = m0 + wr + mi * 16 + quad * 4 + r;
                int col = n0 + wc + ni * 16 + l16;
                C[(size_t)row * N + col] = acc[mi][ni][r];
            }
}

// ---------------------------------------------------------------------------
// attn10: attn7 (proven 60us: 64-row q-tiles, 4 waves x 16 q-rows, 1024
// blocks heavy-first) + PREFETCH-NEXT-TILE double buffering of K/G/V.
// STAGE moved from before the consuming barrier to after it: tile t+1's
// global->LDS loads are in flight during tile t's compute, so the barrier's
// implicit vmcnt(0) drain waits on ~landed loads instead of fresh ones
// (attn7 exposed full HBM latency every k-tile -- the measured 60 vs ~34us
// pipe-floor gap).  LDS 52KB -> 3 blocks/CU (12 waves/CU sustained).
// ---------------------------------------------------------------------------
template<bool DIAG>
static __device__ __forceinline__ void attn_tile(
    const unsigned short* __restrict__ Kc, const unsigned short* __restrict__ Gc,
    const unsigned short* __restrict__ Vc, unsigned short* __restrict__ Pw,
    const bf16x8 (&qf)[2], const bf16x8 (&gf)[2],
    f32x4 (&o)[4], float& lsum,
    int rb, int swz0, int swz1, int pxr, int quad, int l16, int wave,
    int pwb, int pwc)
{
    #pragma unroll
    for (int ni = 0; ni < 4; ++ni) {
        if (DIAG && ni > wave) {
            *(unsigned long long*)&Pw[pwb + (((ni * 2 + pwc) ^ pxr) * 8)] = 0ull;
            continue;
        }
        bf16x8 kf0 = *(const bf16x8*)((const char*)Kc + rb + swz0 + ni * 2048);
        bf16x8 kf1 = *(const bf16x8*)((const char*)Kc + rb + swz1 + ni * 2048);
        bf16x8 gb0 = *(const bf16x8*)((const char*)Gc + rb + swz0 + ni * 2048);
        bf16x8 gb1 = *(const bf16x8*)((const char*)Gc + rb + swz1 + ni * 2048);
        f32x4 a = (f32x4){0.f, 0.f, 0.f, 0.f};
        a = __builtin_amdgcn_mfma_f32_16x16x32_bf16(kf0, qf[0], a, 0, 0, 0);
        a = __builtin_amdgcn_mfma_f32_16x16x32_bf16(gb0, gf[0], a, 0, 0, 0);
        a = __builtin_amdgcn_mfma_f32_16x16x32_bf16(kf1, qf[1], a, 0, 0, 0);
        a = __builtin_amdgcn_mfma_f32_16x16x32_bf16(gb1, gf[1], a, 0, 0, 0);
        float e0, e1, e2, e3;
        if (DIAG && ni == wave) {
            e0 = (quad * 4 + 0 <= l16) ? exp2f(a[0]) : 0.f;
            e1 = (quad * 4 + 1 <= l16) ? exp2f(a[1]) : 0.f;
            e2 = (quad * 4 + 2 <= l16) ? exp2f(a[2]) : 0.f;
            e3 = (quad * 4 + 3 <= l16) ? exp2f(a[3]) : 0.f;
        } else {
            e0 = exp2f(a[0]); e1 = exp2f(a[1]);
            e2 = exp2f(a[2]); e3 = exp2f(a[3]);
        }
        lsum += (e0 + e1) + (e2 + e3);
        unsigned int p01 = pack2bf(e0, e1), p23 = pack2bf(e2, e3);
        *(unsigned long long*)&Pw[pwb + (((ni * 2 + pwc) ^ pxr) * 8)] =
            ((unsigned long long)p23 << 32) | p01;
    }

    // V fragment prefetch overlaps the QK/exp phase (before the P-wait)
    bf16x8 vf[4][2];
    #pragma unroll
    for (int nd = 0; nd < 4; ++nd) {
        vf[nd][0] = *(const bf16x8*)((const char*)Vc + rb + swz0 + nd * 2048);
        vf[nd][1] = *(const bf16x8*)((const char*)Vc + rb + swz1 + nd * 2048);
    }
    asm volatile("s_waitcnt lgkmcnt(0)" ::: "memory");

    bf16x8 pa[2];
    #pragma unroll
    for (int c = 0; c < 2; ++c)
        pa[c] = *(const bf16x8*)&Pw[l16 * 64 + (((c * 4 + quad) ^ pxr) * 8)];
    #pragma unroll
    for (int nd = 0; nd < 4; ++nd) {
        o[nd] = __builtin_amdgcn_mfma_f32_16x16x32_bf16(pa[0], vf[nd][0], o[nd], 0, 0, 0);
        o[nd] = __builtin_amdgcn_mfma_f32_16x16x32_bf16(pa[1], vf[nd][1], o[nd], 0, 0, 0);
    }
}

__global__ __launch_bounds__(256, 3) void attn10(
    const unsigned short* __restrict__ qk, const float* __restrict__ qg,
    const unsigned short* __restrict__ kgb, const unsigned short* __restrict__ vt,
    unsigned short* __restrict__ y)
{
    const int L = 2048, DS = 2048, Dm = 1024;
    const float SC2 = 0.125f * 1.44269504088896f / 7.6246189861593985f;

    const int qt = 31 - (int)blockIdx.y;   // heavy tiles dispatch first
    const int bh = blockIdx.x, b = bh >> 4, h = bh & 15;
    const int tid = threadIdx.x, wave = tid >> 6, lane = tid & 63;
    const int quad = lane >> 4, l16 = lane & 15;

    __shared__ unsigned short K_l[2][4096];   // [64 key][64 hd] swizzled, dbuf
    __shared__ unsigned short G_l[2][4096];
    __shared__ unsigned short V_l[2][4096];   // [hd][key] swizzled, dbuf
    __shared__ unsigned short P_l[4096];      // per-wave [16][64] swizzled
    unsigned short* Pw = &P_l[wave * 1024];

    bf16x8 qf[2], gf[2];
    {
        const int qrow = qt * 64 + wave * 16 + l16;
        const unsigned short* qp = qk + (size_t)(b * L + qrow) * DS + h * 64;
        const float* gp = qg + (size_t)(b * L + qrow) * Dm + h * 64;
        #pragma unroll
        for (int c = 0; c < 2; ++c) {
            qf[c] = scale8v(*(const bf16x8*)(qp + c * 32 + quad * 8), SC2);
            gf[c] = scale8v(cvt8v(gp + c * 32 + quad * 8), SC2);
        }
    }

    f32x4 o[4];
    #pragma unroll
    for (int nd = 0; nd < 4; ++nd) o[nd] = (f32x4){0.f, 0.f, 0.f, 0.f};
    float lsum = 0.f;

    const int srow = wave * 16 + (lane >> 3);
    const int c8 = (((lane & 7) ^ (lane >> 3)) & 7) * 8;
    const unsigned short* pk = qk + (size_t)(b * L + srow) * DS + 1024 + h * 64 + c8;
    const unsigned short* pg = kgb + (size_t)(b * L + srow) * Dm + h * 64 + c8;
    const unsigned short* pv = vt + ((size_t)bh * 64 + srow) * L + c8;

    auto STAGE = [&](int bi) {
        unsigned short* lK = &K_l[bi][wave * 1024];
        unsigned short* lG = &G_l[bi][wave * 1024];
        unsigned short* lV = &V_l[bi][wave * 1024];
        glds16(pk, lK); glds16(pk + 8 * DS, lK + 512);
        glds16(pg, lG); glds16(pg + 8 * Dm, lG + 512);
        glds16(pv, lV); glds16(pv + 8 * L,  lV + 512);
        pk += 64 * DS; pg += 64 * Dm; pv += 64;
    };

    const int rb = l16 * 128;
    const int swz0 = ((quad     ^ (l16 & 7)) * 16);
    const int swz1 = (((4 + quad) ^ (l16 & 7)) * 16);
    // P write: short idx l16*64 + ((ni*2+(quad>>1))^(l16&7))*8 + (quad&1)*4
    const int pwb = l16 * 64 + (quad & 1) * 4;
    const int pwc = quad >> 1, pxr = l16 & 7;

    // prologue: stage tile 0 into buffer 0
    STAGE(0);
    int cur = 0;

    // full (unmasked) k-tiles
    for (int kt = 0; kt < qt; ++kt) {
        __syncthreads();                  // drains cur's loads (in flight 1 tile)
        STAGE(cur ^ 1);                   // prefetch next tile (kt+1; ==qt -> diag)
        attn_tile<false>(&K_l[cur][0], &G_l[cur][0], &V_l[cur][0], Pw,
                         qf, gf, o, lsum, rb, swz0, swz1, pxr, quad, l16, wave,
                         pwb, pwc);
        cur ^= 1;
    }

    // diagonal tile kt == qt (already staged by last loop iter or prologue)
    {
        __syncthreads();
        attn_tile<true>(&K_l[cur][0], &G_l[cur][0], &V_l[cur][0], Pw,
                        qf, gf, o, lsum, rb, swz0, swz1, pxr, quad, l16, wave,
                        pwb, pwc);
    }

    float rs = lsum;
    rs += __shfl_xor(rs, 16);
    rs += __shfl_xor(rs, 32);
    #pragma unroll
    for (int r = 0; r < 4; ++r) {
        float inv = 1.f / __shfl(rs, (lane & 48) | (quad * 4 + r));
        int row = qt * 64 + wave * 16 + quad * 4 + r;
        #pragma unroll
        for (int nd = 0; nd < 4; ++nd)
            y[(size_t)(b * L + row) * Dm + h * 64 + nd * 16 + l16] =
                f2bf(o[nd][r] * inv);
    }
}

// ---------------------------------------------------------------------------
extern "C" void kernel_launch(void* const* d_in, const int* in_sizes, int n_in,
                              void* d_out, int out_size, void* d_ws, size_t ws_size,
                              hipStream_t stream) {
    const float* x     = (const float*)d_in[0];
    const float* q_g   = (const float*)d_in[1];
    const float* k_g   = (const float*)d_in[2];
    const float* W_qkv = (const float*)d_in[3];
    const float* W_out = (const float*)d_in[4];
    float* out = (float*)d_out;
    unsigned short* ws = (unsigned short*)d_ws;

    unsigned short* qk_ws = ws;                  // [4096][2048]  Q|K
    unsigned short* y_ws  = ws + 8388608;        // [4096][1024]
    unsigned short* wtq   = ws + 12582912;       // [3072][1024]
    unsigned short* wto   = ws + 15728640;       // [1024][1024]
    unsigned short* kg_bf = ws + 16777216;       // [4096][1024]
    unsigned short* x_bf  = ws + 20971520;       // [4096][1024]
    unsigned short* vt_bf = ws + 25165824;       // [32][64][2048]

    dim3 blk(256);
    prep_all<<<5120, blk, 0, stream>>>(x, x_bf, k_g, kg_bf, W_qkv, wtq, W_out, wto);
    gemm_qkv<<<dim3(24, 32), blk, 0, stream>>>(x_bf, wtq, qk_ws, vt_bf);
    attn10<<<dim3(32, 32), blk, 0, stream>>>(qk_ws, q_g, kg_bf, vt_bf, y_ws);
    gemm_n64<<<dim3(16, 32), blk, 0, stream>>>(y_ws, wto, out);
}

// Round 5
// 228.817 us; speedup vs baseline: 1.0557x; 1.0346x over previous
//
#include <hip/hip_runtime.h>

typedef __attribute__((ext_vector_type(8))) short bf16x8;
typedef __attribute__((ext_vector_type(4))) float f32x4;

static __device__ __forceinline__ unsigned short f2bf(float f) {
    unsigned int u = __float_as_uint(f);
    u += 0x7fffu + ((u >> 16) & 1u);
    return (unsigned short)(u >> 16);
}
// round-half-up: P-values only (|rel err| <= 2^-9, tolerance-safe)
static __device__ __forceinline__ unsigned int pack2bf(float lo, float hi) {
    return ((__float_as_uint(lo) + 0x8000u) >> 16) |
           ((__float_as_uint(hi) + 0x8000u) & 0xffff0000u);
}
static __device__ __forceinline__ float bf2f(short v) {
    return __uint_as_float(((unsigned int)(unsigned short)v) << 16);
}
static __device__ __forceinline__ bf16x8 cvt8v(const float* p) {
    f32x4 a = *(const f32x4*)p, b = *(const f32x4*)(p + 4);
    bf16x8 r;
    r[0] = (short)f2bf(a[0]); r[1] = (short)f2bf(a[1]);
    r[2] = (short)f2bf(a[2]); r[3] = (short)f2bf(a[3]);
    r[4] = (short)f2bf(b[0]); r[5] = (short)f2bf(b[1]);
    r[6] = (short)f2bf(b[2]); r[7] = (short)f2bf(b[3]);
    return r;
}
static __device__ __forceinline__ bf16x8 scale8v(bf16x8 v, float s) {
    bf16x8 r;
    #pragma unroll
    for (int j = 0; j < 8; ++j) r[j] = (short)f2bf(bf2f(v[j]) * s);
    return r;
}
static __device__ __forceinline__ uint4 cvt8(const float* p) {
    bf16x8 r = cvt8v(p);
    union { bf16x8 v; uint4 u; } c; c.v = r; return c.u;
}
// async global->LDS, 16B/lane; LDS dest = wave-uniform base + lane*16
static __device__ __forceinline__ void glds16(const unsigned short* g, unsigned short* l) {
    __builtin_amdgcn_global_load_lds(
        (const __attribute__((address_space(1))) unsigned int*)g,
        (__attribute__((address_space(3))) unsigned int*)l, 16, 0, 0);
}

// ---------------------------------------------------------------------------
// Fused prep: cvt x -> x_bf, cvt k_g -> kg_bf, transpose+cvt W_qkv, W_out.
// grid 5120: [0,2048) x | [2048,4096) k_g | [4096,4864) Wqkv | [4864,5120) Wout
// ---------------------------------------------------------------------------
static __device__ __forceinline__ void transpose_tile(
    const float* __restrict__ src, unsigned short* __restrict__ dst,
    int R, int C, int bx, int by, int tid)
{
    __shared__ unsigned short t[64 * 72];
    const int r0 = by * 64, c0 = bx * 64;
    #pragma unroll
    for (int i = 0; i < 4; ++i) {
        int idx = tid + i * 256;
        int row = idx >> 4, seg = idx & 15;
        f32x4 v = *(const f32x4*)&src[(size_t)(r0 + row) * C + c0 + seg * 4];
        #pragma unroll
        for (int j = 0; j < 4; ++j) t[row * 72 + seg * 4 + j] = f2bf(v[j]);
    }
    __syncthreads();
    #pragma unroll
    for (int i = 0; i < 2; ++i) {
        int idx = tid + i * 256;
        int row = idx >> 3, seg = idx & 7;
        uint4 tv; unsigned short* tmp = (unsigned short*)&tv;
        #pragma unroll
        for (int j = 0; j < 8; ++j) tmp[j] = t[(seg * 8 + j) * 72 + row];
        *(uint4*)&dst[(size_t)(c0 + row) * R + r0 + seg * 8] = tv;
    }
}

__global__ __launch_bounds__(256) void prep_all(
    const float* __restrict__ x, unsigned short* __restrict__ x_bf,
    const float* __restrict__ kg, unsigned short* __restrict__ kg_bf,
    const float* __restrict__ Wq, unsigned short* __restrict__ wtq,
    const float* __restrict__ Wo, unsigned short* __restrict__ wto)
{
    const int t = blockIdx.x, tid = threadIdx.x;
    if (t < 2048) {
        size_t j = ((size_t)t * 256 + tid) * 8;
        *(uint4*)&x_bf[j] = cvt8(&x[j]);
    } else if (t < 4096) {
        size_t j = ((size_t)(t - 2048) * 256 + tid) * 8;
        *(uint4*)&kg_bf[j] = cvt8(&kg[j]);
    } else if (t < 4864) {
        int tt = t - 4096;               // W_qkv [1024][3072]: 48 col-tiles x 16
        transpose_tile(Wq, wtq, 1024, 3072, tt % 48, tt / 48, tid);
    } else {
        int tt = t - 4864;               // W_out [1024][1024]
        transpose_tile(Wo, wto, 1024, 1024, tt & 15, tt >> 4, tid);
    }
}

// ---------------------------------------------------------------------------
// gemm_qkv: qkv = x_bf @ wtq^T.  Q,K cols (wx<16) -> qk[4096][2048].
// V cols (wx>=16) -> written TRANSPOSED to vt[bh][hd=64][L=2048] via LDS.
// Round-5: BK=64 (barrier pairs 32->16), Tb aliased over As/Bs (LDS 35KB ->
// 4 blocks/CU), XCD-aware block swizzle (768 blocks, 96/XCD, bijective).
// ---------------------------------------------------------------------------
__global__ __launch_bounds__(256) void gemm_qkv(
    const unsigned short* __restrict__ A, const unsigned short* __restrict__ Bt,
    unsigned short* __restrict__ qk, unsigned short* __restrict__ vt)
{
    const int K = 1024;
    __shared__ unsigned short U[128 * 136];    // As[128*64] | Bs[128*64]; Tb aliases
    unsigned short* As = U;
    unsigned short* Bs = U + 8192;
    unsigned short* Tb = U;                    // epilogue-only reuse (after barrier)
    const int tid = threadIdx.x;
    const int wave = tid >> 6, lane = tid & 63, quad = lane >> 4, l16 = lane & 15;
    const int wr = (wave >> 1) * 64, wc = (wave & 1) * 64;

    // XCD swizzle: lin%8 = hw XCD -> contiguous work chunk per XCD
    const int lin = (int)blockIdx.y * 24 + (int)blockIdx.x;   // 768 blocks
    const int wl = (lin & 7) * 96 + (lin >> 3);
    const int wx = wl % 24, wy = wl / 24;
    const int m0 = wy * 128, n0 = wx * 128;

    const unsigned short* ga = A  + (size_t)(m0 + wave * 32 + (lane >> 3)) * K + (lane & 7) * 8;
    const unsigned short* gb = Bt + (size_t)(n0 + wave * 32 + (lane >> 3)) * K + (lane & 7) * 8;
    unsigned short* la = As + wave * 32 * 64;
    unsigned short* lb = Bs + wave * 32 * 64;
    const size_t step8 = (size_t)8 * K;

    f32x4 acc[4][4];
    #pragma unroll
    for (int i = 0; i < 4; ++i)
        #pragma unroll
        for (int j = 0; j < 4; ++j) acc[i][j] = (f32x4){0.f, 0.f, 0.f, 0.f};

    for (int kt = 0; kt < K; kt += 64) {
        #pragma unroll
        for (int g = 0; g < 4; ++g) {
            glds16(ga + g * step8, la + g * 512);
            glds16(gb + g * step8, lb + g * 512);
        }
        ga += 64; gb += 64;
        __syncthreads();
        #pragma unroll
        for (int h = 0; h < 2; ++h) {
            bf16x8 af[4], bf[4];
            #pragma unroll
            for (int i = 0; i < 4; ++i) {
                af[i] = *(const bf16x8*)&As[(wr + i * 16 + l16) * 64 + h * 32 + quad * 8];
                bf[i] = *(const bf16x8*)&Bs[(wc + i * 16 + l16) * 64 + h * 32 + quad * 8];
            }
            #pragma unroll
            for (int mi = 0; mi < 4; ++mi)
                #pragma unroll
                for (int ni = 0; ni < 4; ++ni)
                    acc[mi][ni] = __builtin_amdgcn_mfma_f32_16x16x32_bf16(
                        af[mi], bf[ni], acc[mi][ni], 0, 0, 0);
        }
        __syncthreads();
    }

    if (wx < 16) {                // Q|K part: normal write, stride 2048
        #pragma unroll
        for (int mi = 0; mi < 4; ++mi)
            #pragma unroll
            for (int ni = 0; ni < 4; ++ni)
                #pragma unroll
                for (int r = 0; r < 4; ++r) {
                    int row = m0 + wr + mi * 16 + quad * 4 + r;
                    int col = n0 + wc + ni * 16 + l16;
                    qk[(size_t)row * 2048 + col] = f2bf(acc[mi][ni][r]);
                }
    } else {                      // V part: transpose via LDS -> vt[bh][hd][L]
        __syncthreads();          // all waves done reading As/Bs before Tb alias
        #pragma unroll
        for (int mi = 0; mi < 4; ++mi)
            #pragma unroll
            for (int ni = 0; ni < 4; ++ni)
                #pragma unroll
                for (int r = 0; r < 4; ++r) {
                    int col = wc + ni * 16 + l16;            // hd-ish (0..127)
                    int row = wr + mi * 16 + quad * 4 + r;   // pos (0..127)
                    Tb[col * 136 + row] = f2bf(acc[mi][ni][r]);
                }
        __syncthreads();
        const int col = tid >> 1, r0 = (tid & 1) * 64;
        const int bh = (m0 >> 11) * 16 + (wx - 16) * 2 + (col >> 6);
        size_t base = ((size_t)bh * 64 + (col & 63)) * 2048 + (m0 & 2047) + r0;
        #pragma unroll
        for (int k = 0; k < 8; ++k)
            *(uint4*)&vt[base + k * 8] = *(const uint4*)&Tb[col * 136 + r0 + k * 8];
    }
}

// ---------------------------------------------------------------------------
// gemm2: out = y_ws @ wto^T, f32 out.  Round-5: 64x64 tiles, BK=64 ->
// 1024 blocks (4/CU by grid vs 2/CU before), LDS 16KB, barrier pairs 16.
// 4 waves: 2x2, each 32x32.
// ---------------------------------------------------------------------------
__global__ __launch_bounds__(256) void gemm_n64(
    const unsigned short* __restrict__ A, const unsigned short* __restrict__ Bt,
    float* __restrict__ C)
{
    const int K = 1024, N = 1024;
    __shared__ unsigned short As[64 * 64];
    __shared__ unsigned short Bs[64 * 64];
    const int tid = threadIdx.x;
    const int wave = tid >> 6, lane = tid & 63, quad = lane >> 4, l16 = lane & 15;
    const int wr = (wave >> 1) * 32, wc = (wave & 1) * 32;

    // XCD swizzle: 1024 blocks, 128/XCD
    const int lin = (int)blockIdx.y * 16 + (int)blockIdx.x;
    const int wl = (lin & 7) * 128 + (lin >> 3);
    const int wx = wl & 15, wy = wl >> 4;
    const int m0 = wy * 64, n0 = wx * 64;

    const unsigned short* ga = A  + (size_t)(m0 + wave * 16 + (lane >> 3)) * K + (lane & 7) * 8;
    const unsigned short* gb = Bt + (size_t)(n0 + wave * 16 + (lane >> 3)) * K + (lane & 7) * 8;
    unsigned short* la = &As[wave * 16 * 64];
    unsigned short* lb = &Bs[wave * 16 * 64];
    const size_t step8 = (size_t)8 * K;

    f32x4 acc[2][2];
    #pragma unroll
    for (int i = 0; i < 2; ++i)
        #pragma unroll
        for (int j = 0; j < 2; ++j) acc[i][j] = (f32x4){0.f, 0.f, 0.f, 0.f};

    for (int kt = 0; kt < K; kt += 64) {
        glds16(ga, la); glds16(ga + step8, la + 512);
        glds16(gb, lb); glds16(gb + step8, lb + 512);
        ga += 64; gb += 64;
        __syncthreads();
        #pragma unroll
        for (int h = 0; h < 2; ++h) {
            bf16x8 af[2], bf[2];
            #pragma unroll
            for (int i = 0; i < 2; ++i) {
                af[i] = *(const bf16x8*)&As[(wr + i * 16 + l16) * 64 + h * 32 + quad * 8];
                bf[i] = *(const bf16x8*)&Bs[(wc + i * 16 + l16) * 64 + h * 32 + quad * 8];
            }
            #pragma unroll
            for (int mi = 0; mi < 2; ++mi)
                #pragma unroll
                for (int ni = 0; ni < 2; ++ni)
                    acc[mi][ni] = __builtin_amdgcn_mfma_f32_16x16x32_bf16(
                        af[mi], bf[ni], acc[mi][ni], 0, 0, 0);
        }
        __syncthreads();
    }
    #pragma unroll
    for (int mi = 0; mi < 2; ++mi)
        #pragma unroll
        for (int ni = 0; ni < 2; ++ni)
            #pragma unroll
            for (int r = 0; r < 4; ++r) {
                int row = m0 + wr + mi * 16 + quad * 4 + r;
                int col = n0 + wc + ni * 16 + l16;
                C[(size_t)row * N + col] = acc[mi][ni][r];
            }
}

// ---------------------------------------------------------------------------
// Dual-score causal flash attention (attn7, proven 60us): 64-row q-tiles,
// 1024 blocks, 4 waves x 16 q-rows, P buffer [16][64]/wave XOR chunk-swizzle,
// LDS exactly 32768 B -> 5 blocks/CU; S computed transposed; mask hoisted to
// diagonal tile; fixed-base softmax.
// ---------------------------------------------------------------------------
__global__ __launch_bounds__(256, 5) void attn7(
    const unsigned short* __restrict__ qk, const float* __restrict__ qg,
    const unsigned short* __restrict__ kgb, const unsigned short* __restrict__ vt,
    unsigned short* __restrict__ y)
{
    const int L = 2048, DS = 2048, Dm = 1024;
    const float SC2 = 0.125f * 1.44269504088896f / 7.6246189861593985f;

    const int qt = 31 - (int)blockIdx.y;   // heavy tiles dispatch first
    const int bh = blockIdx.x, b = bh >> 4, h = bh & 15;
    const int tid = threadIdx.x, wave = tid >> 6, lane = tid & 63;
    const int quad = lane >> 4, l16 = lane & 15;

    __shared__ unsigned short K_l[4096];     // [64][64] swizzled
    __shared__ unsigned short G_l[4096];
    __shared__ unsigned short V_l[4096];     // [hd][key] swizzled
    __shared__ unsigned short P_l[4096];     // per-wave [16][64] swizzled
    unsigned short* Pw = &P_l[wave * 1024];

    bf16x8 qf[2], gf[2];
    {
        const int qrow = qt * 64 + wave * 16 + l16;
        const unsigned short* qp = qk + (size_t)(b * L + qrow) * DS + h * 64;
        const float* gp = qg + (size_t)(b * L + qrow) * Dm + h * 64;
        #pragma unroll
        for (int c = 0; c < 2; ++c) {
            qf[c] = scale8v(*(const bf16x8*)(qp + c * 32 + quad * 8), SC2);
            gf[c] = scale8v(cvt8v(gp + c * 32 + quad * 8), SC2);
        }
    }

    f32x4 o[4];
    #pragma unroll
    for (int nd = 0; nd < 4; ++nd) o[nd] = (f32x4){0.f, 0.f, 0.f, 0.f};
    float lsum = 0.f;

    const int srow = wave * 16 + (lane >> 3);
    const int c8 = (((lane & 7) ^ (lane >> 3)) & 7) * 8;
    const unsigned short* pk = qk + (size_t)(b * L + srow) * DS + 1024 + h * 64 + c8;
    const unsigned short* pg = kgb + (size_t)(b * L + srow) * Dm + h * 64 + c8;
    const unsigned short* pv = vt + ((size_t)bh * 64 + srow) * L + c8;
    unsigned short* lK = &K_l[wave * 1024];
    unsigned short* lG = &G_l[wave * 1024];
    unsigned short* lV = &V_l[wave * 1024];

    const int rb = l16 * 128;
    const int swz0 = ((quad     ^ (l16 & 7)) * 16);
    const int swz1 = (((4 + quad) ^ (l16 & 7)) * 16);
    // P write: short idx l16*64 + ((ni*2+(quad>>1))^(l16&7))*8 + (quad&1)*4
    const int pwb = l16 * 64 + (quad & 1) * 4;
    const int pwc = quad >> 1, pxr = l16 & 7;

    for (int kt = 0; kt < qt; ++kt) {
        __syncthreads();
        glds16(pk, lK); glds16(pk + 8 * DS, lK + 512);
        glds16(pg, lG); glds16(pg + 8 * Dm, lG + 512);
        glds16(pv, lV); glds16(pv + 8 * L,  lV + 512);
        pk += 64 * DS; pg += 64 * Dm; pv += 64;
        __syncthreads();

        #pragma unroll
        for (int ni = 0; ni < 4; ++ni) {
            bf16x8 kf0 = *(const bf16x8*)((const char*)K_l + rb + swz0 + ni * 2048);
            bf16x8 kf1 = *(const bf16x8*)((const char*)K_l + rb + swz1 + ni * 2048);
            bf16x8 gb0 = *(const bf16x8*)((const char*)G_l + rb + swz0 + ni * 2048);
            bf16x8 gb1 = *(const bf16x8*)((const char*)G_l + rb + swz1 + ni * 2048);
            f32x4 a = (f32x4){0.f, 0.f, 0.f, 0.f};
            a = __builtin_amdgcn_mfma_f32_16x16x32_bf16(kf0, qf[0], a, 0, 0, 0);
            a = __builtin_amdgcn_mfma_f32_16x16x32_bf16(gb0, gf[0], a, 0, 0, 0);
            a = __builtin_amdgcn_mfma_f32_16x16x32_bf16(kf1, qf[1], a, 0, 0, 0);
            a = __builtin_amdgcn_mfma_f32_16x16x32_bf16(gb1, gf[1], a, 0, 0, 0);
            float e0 = exp2f(a[0]), e1 = exp2f(a[1]);
            float e2 = exp2f(a[2]), e3 = exp2f(a[3]);
            lsum += (e0 + e1) + (e2 + e3);
            unsigned int p01 = pack2bf(e0, e1), p23 = pack2bf(e2, e3);
            *(unsigned long long*)&Pw[pwb + (((ni * 2 + pwc) ^ pxr) * 8)] =
                ((unsigned long long)p23 << 32) | p01;
        }
        asm volatile("s_waitcnt lgkmcnt(0)" ::: "memory");

        bf16x8 pa[2];
        #pragma unroll
        for (int c = 0; c < 2; ++c)
            pa[c] = *(const bf16x8*)&Pw[l16 * 64 + (((c * 4 + quad) ^ pxr) * 8)];
        #pragma unroll
        for (int nd = 0; nd < 4; ++nd) {
            bf16x8 vf0 = *(const bf16x8*)((const char*)V_l + rb + swz0 + nd * 2048);
            bf16x8 vf1 = *(const bf16x8*)((const char*)V_l + rb + swz1 + nd * 2048);
            o[nd] = __builtin_amdgcn_mfma_f32_16x16x32_bf16(pa[0], vf0, o[nd], 0, 0, 0);
            o[nd] = __builtin_amdgcn_mfma_f32_16x16x32_bf16(pa[1], vf1, o[nd], 0, 0, 0);
        }
    }

    // ---- diagonal tile kt == qt ----
    {
        __syncthreads();
        glds16(pk, lK); glds16(pk + 8 * DS, lK + 512);
        glds16(pg, lG); glds16(pg + 8 * Dm, lG + 512);
        glds16(pv, lV); glds16(pv + 8 * L,  lV + 512);
        __syncthreads();

        #pragma unroll
        for (int ni = 0; ni < 4; ++ni) {
            if (ni > wave) {
                *(unsigned long long*)&Pw[pwb + (((ni * 2 + pwc) ^ pxr) * 8)] = 0ull;
                continue;
            }
            bf16x8 kf0 = *(const bf16x8*)((const char*)K_l + rb + swz0 + ni * 2048);
            bf16x8 kf1 = *(const bf16x8*)((const char*)K_l + rb + swz1 + ni * 2048);
            bf16x8 gb0 = *(const bf16x8*)((const char*)G_l + rb + swz0 + ni * 2048);
            bf16x8 gb1 = *(const bf16x8*)((const char*)G_l + rb + swz1 + ni * 2048);
            f32x4 a = (f32x4){0.f, 0.f, 0.f, 0.f};
            a = __builtin_amdgcn_mfma_f32_16x16x32_bf16(kf0, qf[0], a, 0, 0, 0);
            a = __builtin_amdgcn_mfma_f32_16x16x32_bf16(gb0, gf[0], a, 0, 0, 0);
            a = __builtin_amdgcn_mfma_f32_16x16x32_bf16(kf1, qf[1], a, 0, 0, 0);
            a = __builtin_amdgcn_mfma_f32_16x16x32_bf16(gb1, gf[1], a, 0, 0, 0);
            float e0, e1, e2, e3;
            if (ni < wave) {
                e0 = exp2f(a[0]); e1 = exp2f(a[1]);
                e2 = exp2f(a[2]); e3 = exp2f(a[3]);
            } else {
                e0 = (quad * 4 + 0 <= l16) ? exp2f(a[0]) : 0.f;
                e1 = (quad * 4 + 1 <= l16) ? exp2f(a[1]) : 0.f;
                e2 = (quad * 4 + 2 <= l16) ? exp2f(a[2]) : 0.f;
                e3 = (quad * 4 + 3 <= l16) ? exp2f(a[3]) : 0.f;
            }
            lsum += (e0 + e1) + (e2 + e3);
            unsigned int p01 = pack2bf(e0, e1), p23 = pack2bf(e2, e3);
            *(unsigned long long*)&Pw[pwb + (((ni * 2 + pwc) ^ pxr) * 8)] =
                ((unsigned long long)p23 << 32) | p01;
        }
        asm volatile("s_waitcnt lgkmcnt(0)" ::: "memory");

        bf16x8 pa[2];
        #pragma unroll
        for (int c = 0; c < 2; ++c)
            pa[c] = *(const bf16x8*)&Pw[l16 * 64 + (((c * 4 + quad) ^ pxr) * 8)];
        #pragma unroll
        for (int nd = 0; nd < 4; ++nd) {
            bf16x8 vf0 = *(const bf16x8*)((const char*)V_l + rb + swz0 + nd * 2048);
            bf16x8 vf1 = *(const bf16x8*)((const char*)V_l + rb + swz1 + nd * 2048);
            o[nd] = __builtin_amdgcn_mfma_f32_16x16x32_bf16(pa[0], vf0, o[nd], 0, 0, 0);
            o[nd] = __builtin_amdgcn_mfma_f32_16x16x32_bf16(pa[1], vf1, o[nd], 0, 0, 0);
        }
    }

    float rs = lsum;
    rs += __shfl_xor(rs, 16);
    rs += __shfl_xor(rs, 32);
    #pragma unroll
    for (int r = 0; r < 4; ++r) {
        float inv = 1.f / __shfl(rs, (lane & 48) | (quad * 4 + r));
        int row = qt * 64 + wave * 16 + quad * 4 + r;
        #pragma unroll
        for (int nd = 0; nd < 4; ++nd)
            y[(size_t)(b * L + row) * Dm + h * 64 + nd * 16 + l16] =
                f2bf(o[nd][r] * inv);
    }
}

// ---------------------------------------------------------------------------
extern "C" void kernel_launch(void* const* d_in, const int* in_sizes, int n_in,
                              void* d_out, int out_size, void* d_ws, size_t ws_size,
                              hipStream_t stream) {
    const float* x     = (const float*)d_in[0];
    const float* q_g   = (const float*)d_in[1];
    const float* k_g   = (const float*)d_in[2];
    const float* W_qkv = (const float*)d_in[3];
    const float* W_out = (const float*)d_in[4];
    float* out = (float*)d_out;
    unsigned short* ws = (unsigned short*)d_ws;

    unsigned short* qk_ws = ws;                  // [4096][2048]  Q|K
    unsigned short* y_ws  = ws + 8388608;        // [4096][1024]
    unsigned short* wtq   = ws + 12582912;       // [3072][1024]
    unsigned short* wto   = ws + 15728640;       // [1024][1024]
    unsigned short* kg_bf = ws + 16777216;       // [4096][1024]
    unsigned short* x_bf  = ws + 20971520;       // [4096][1024]
    unsigned short* vt_bf = ws + 25165824;       // [32][64][2048]

    dim3 blk(256);
    prep_all<<<5120, blk, 0, stream>>>(x, x_bf, k_g, kg_bf, W_qkv, wtq, W_out, wto);
    gemm_qkv<<<dim3(24, 32), blk, 0, stream>>>(x_bf, wtq, qk_ws, vt_bf);
    attn7<<<dim3(32, 32), blk, 0, stream>>>(qk_ws, q_g, kg_bf, vt_bf, y_ws);
    gemm_n64<<<dim3(16, 64), blk, 0, stream>>>(y_ws, wto, out);
}

// Round 6
// 226.004 us; speedup vs baseline: 1.0688x; 1.0124x over previous
//
#include <hip/hip_runtime.h>

typedef __attribute__((ext_vector_type(8))) short bf16x8;
typedef __attribute__((ext_vector_type(4))) float f32x4;

static __device__ __forceinline__ unsigned short f2bf(float f) {
    unsigned int u = __float_as_uint(f);
    u += 0x7fffu + ((u >> 16) & 1u);
    return (unsigned short)(u >> 16);
}
// round-half-up: P-values only (|rel err| <= 2^-9, tolerance-safe)
static __device__ __forceinline__ unsigned int pack2bf(float lo, float hi) {
    return ((__float_as_uint(lo) + 0x8000u) >> 16) |
           ((__float_as_uint(hi) + 0x8000u) & 0xffff0000u);
}
static __device__ __forceinline__ float bf2f(short v) {
    return __uint_as_float(((unsigned int)(unsigned short)v) << 16);
}
static __device__ __forceinline__ bf16x8 cvt8v(const float* p) {
    f32x4 a = *(const f32x4*)p, b = *(const f32x4*)(p + 4);
    bf16x8 r;
    r[0] = (short)f2bf(a[0]); r[1] = (short)f2bf(a[1]);
    r[2] = (short)f2bf(a[2]); r[3] = (short)f2bf(a[3]);
    r[4] = (short)f2bf(b[0]); r[5] = (short)f2bf(b[1]);
    r[6] = (short)f2bf(b[2]); r[7] = (short)f2bf(b[3]);
    return r;
}
static __device__ __forceinline__ bf16x8 scale8v(bf16x8 v, float s) {
    bf16x8 r;
    #pragma unroll
    for (int j = 0; j < 8; ++j) r[j] = (short)f2bf(bf2f(v[j]) * s);
    return r;
}
static __device__ __forceinline__ uint4 cvt8(const float* p) {
    bf16x8 r = cvt8v(p);
    union { bf16x8 v; uint4 u; } c; c.v = r; return c.u;
}
// async global->LDS, 16B/lane; LDS dest = wave-uniform base + lane*16
static __device__ __forceinline__ void glds16(const unsigned short* g, unsigned short* l) {
    __builtin_amdgcn_global_load_lds(
        (const __attribute__((address_space(1))) unsigned int*)g,
        (__attribute__((address_space(3))) unsigned int*)l, 16, 0, 0);
}

// ---------------------------------------------------------------------------
// Fused prep: cvt x -> x_bf, cvt k_g -> kg_bf, transpose+cvt W_qkv, W_out.
// grid 5120: [0,2048) x | [2048,4096) k_g | [4096,4864) Wqkv | [4864,5120) Wout
// ---------------------------------------------------------------------------
static __device__ __forceinline__ void transpose_tile(
    const float* __restrict__ src, unsigned short* __restrict__ dst,
    int R, int C, int bx, int by, int tid)
{
    __shared__ unsigned short t[64 * 72];
    const int r0 = by * 64, c0 = bx * 64;
    #pragma unroll
    for (int i = 0; i < 4; ++i) {
        int idx = tid + i * 256;
        int row = idx >> 4, seg = idx & 15;
        f32x4 v = *(const f32x4*)&src[(size_t)(r0 + row) * C + c0 + seg * 4];
        #pragma unroll
        for (int j = 0; j < 4; ++j) t[row * 72 + seg * 4 + j] = f2bf(v[j]);
    }
    __syncthreads();
    #pragma unroll
    for (int i = 0; i < 2; ++i) {
        int idx = tid + i * 256;
        int row = idx >> 3, seg = idx & 7;
        uint4 tv; unsigned short* tmp = (unsigned short*)&tv;
        #pragma unroll
        for (int j = 0; j < 8; ++j) tmp[j] = t[(seg * 8 + j) * 72 + row];
        *(uint4*)&dst[(size_t)(c0 + row) * R + r0 + seg * 8] = tv;
    }
}

__global__ __launch_bounds__(256) void prep_all(
    const float* __restrict__ x, unsigned short* __restrict__ x_bf,
    const float* __restrict__ kg, unsigned short* __restrict__ kg_bf,
    const float* __restrict__ Wq, unsigned short* __restrict__ wtq,
    const float* __restrict__ Wo, unsigned short* __restrict__ wto)
{
    const int t = blockIdx.x, tid = threadIdx.x;
    if (t < 2048) {
        size_t j = ((size_t)t * 256 + tid) * 8;
        *(uint4*)&x_bf[j] = cvt8(&x[j]);
    } else if (t < 4096) {
        size_t j = ((size_t)(t - 2048) * 256 + tid) * 8;
        *(uint4*)&kg_bf[j] = cvt8(&kg[j]);
    } else if (t < 4864) {
        int tt = t - 4096;               // W_qkv [1024][3072]: 48 col-tiles x 16
        transpose_tile(Wq, wtq, 1024, 3072, tt % 48, tt / 48, tid);
    } else {
        int tt = t - 4864;               // W_out [1024][1024]
        transpose_tile(Wo, wto, 1024, 1024, tt & 15, tt >> 4, tid);
    }
}

// ---------------------------------------------------------------------------
// gemm_qkv: qkv = x_bf @ wtq^T.  Q,K cols (bx<16) -> qk[4096][2048].
// V cols (bx>=16) -> written TRANSPOSED to vt[bh][hd=64][L=2048] via LDS.
// 128x128 tile, BK=32, glds16 staging (m97 pattern).
// ---------------------------------------------------------------------------
__global__ __launch_bounds__(256) void gemm_qkv(
    const unsigned short* __restrict__ A, const unsigned short* __restrict__ Bt,
    unsigned short* __restrict__ qk, unsigned short* __restrict__ vt)
{
    const int K = 1024;
    __shared__ unsigned short As[128 * 32];
    __shared__ unsigned short Bs[128 * 32];
    __shared__ unsigned short Tb[128 * 136];   // V-transpose scratch
    const int tid = threadIdx.x;
    const int wave = tid >> 6, lane = tid & 63, quad = lane >> 4, l16 = lane & 15;
    const int wr = (wave >> 1) * 64, wc = (wave & 1) * 64;
    const int m0 = blockIdx.y * 128, n0 = blockIdx.x * 128;

    const unsigned short* ga = A  + (size_t)(m0 + wave * 32 + (lane >> 2)) * K + (lane & 3) * 8;
    const unsigned short* gb = Bt + (size_t)(n0 + wave * 32 + (lane >> 2)) * K + (lane & 3) * 8;
    unsigned short* la = &As[wave * 32 * 32];
    unsigned short* lb = &Bs[wave * 32 * 32];
    const size_t step16 = (size_t)16 * K;

    f32x4 acc[4][4];
    #pragma unroll
    for (int i = 0; i < 4; ++i)
        #pragma unroll
        for (int j = 0; j < 4; ++j) acc[i][j] = (f32x4){0.f, 0.f, 0.f, 0.f};

    for (int kt = 0; kt < K; kt += 32) {
        glds16(ga, la); glds16(ga + step16, la + 512);
        glds16(gb, lb); glds16(gb + step16, lb + 512);
        ga += 32; gb += 32;
        __syncthreads();
        bf16x8 af[4], bf[4];
        #pragma unroll
        for (int i = 0; i < 4; ++i) {
            af[i] = *(const bf16x8*)&As[(wr + i * 16 + l16) * 32 + quad * 8];
            bf[i] = *(const bf16x8*)&Bs[(wc + i * 16 + l16) * 32 + quad * 8];
        }
        #pragma unroll
        for (int mi = 0; mi < 4; ++mi)
            #pragma unroll
            for (int ni = 0; ni < 4; ++ni)
                acc[mi][ni] = __builtin_amdgcn_mfma_f32_16x16x32_bf16(
                    af[mi], bf[ni], acc[mi][ni], 0, 0, 0);
        __syncthreads();
    }

    if (blockIdx.x < 16) {        // Q|K part: normal write, stride 2048
        #pragma unroll
        for (int mi = 0; mi < 4; ++mi)
            #pragma unroll
            for (int ni = 0; ni < 4; ++ni)
                #pragma unroll
                for (int r = 0; r < 4; ++r) {
                    int row = m0 + wr + mi * 16 + quad * 4 + r;
                    int col = n0 + wc + ni * 16 + l16;
                    qk[(size_t)row * 2048 + col] = f2bf(acc[mi][ni][r]);
                }
    } else {                      // V part: transpose via LDS -> vt[bh][hd][L]
        __syncthreads();
        #pragma unroll
        for (int mi = 0; mi < 4; ++mi)
            #pragma unroll
            for (int ni = 0; ni < 4; ++ni)
                #pragma unroll
                for (int r = 0; r < 4; ++r) {
                    int col = wc + ni * 16 + l16;            // hd-ish (0..127)
                    int row = wr + mi * 16 + quad * 4 + r;   // pos (0..127)
                    Tb[col * 136 + row] = f2bf(acc[mi][ni][r]);
                }
        __syncthreads();
        const int col = tid >> 1, r0 = (tid & 1) * 64;
        const int bh = (m0 >> 11) * 16 + ((int)blockIdx.x - 16) * 2 + (col >> 6);
        size_t base = ((size_t)bh * 64 + (col & 63)) * 2048 + (m0 & 2047) + r0;
        #pragma unroll
        for (int k = 0; k < 8; ++k)
            *(uint4*)&vt[base + k * 8] = *(const uint4*)&Tb[col * 136 + r0 + k * 8];
    }
}

// ---------------------------------------------------------------------------
// gemm2: out = y_ws @ wto^T, f32 out.  128(M) x 64(N) tile -> 512 blocks, 2/CU.
// 4 waves: 2x2, each 64x32.
// ---------------------------------------------------------------------------
__global__ __launch_bounds__(256) void gemm_n64(
    const unsigned short* __restrict__ A, const unsigned short* __restrict__ Bt,
    float* __restrict__ C)
{
    const int K = 1024, N = 1024;
    __shared__ unsigned short As[128 * 32];
    __shared__ unsigned short Bs[64 * 32];
    const int tid = threadIdx.x;
    const int wave = tid >> 6, lane = tid & 63, quad = lane >> 4, l16 = lane & 15;
    const int wr = (wave >> 1) * 64, wc = (wave & 1) * 32;
    const int m0 = blockIdx.y * 128, n0 = blockIdx.x * 64;

    const unsigned short* ga = A  + (size_t)(m0 + wave * 32 + (lane >> 2)) * K + (lane & 3) * 8;
    const unsigned short* gb = Bt + (size_t)(n0 + wave * 16 + (lane >> 2)) * K + (lane & 3) * 8;
    unsigned short* la = &As[wave * 32 * 32];
    unsigned short* lb = &Bs[wave * 16 * 32];
    const size_t step16 = (size_t)16 * K;

    f32x4 acc[4][2];
    #pragma unroll
    for (int i = 0; i < 4; ++i)
        #pragma unroll
        for (int j = 0; j < 2; ++j) acc[i][j] = (f32x4){0.f, 0.f, 0.f, 0.f};

    for (int kt = 0; kt < K; kt += 32) {
        glds16(ga, la); glds16(ga + step16, la + 512);
        glds16(gb, lb);
        ga += 32; gb += 32;
        __syncthreads();
        bf16x8 af[4], bf[2];
        #pragma unroll
        for (int i = 0; i < 4; ++i)
            af[i] = *(const bf16x8*)&As[(wr + i * 16 + l16) * 32 + quad * 8];
        #pragma unroll
        for (int i = 0; i < 2; ++i)
            bf[i] = *(const bf16x8*)&Bs[(wc + i * 16 + l16) * 32 + quad * 8];
        #pragma unroll
        for (int mi = 0; mi < 4; ++mi)
            #pragma unroll
            for (int ni = 0; ni < 2; ++ni)
                acc[mi][ni] = __builtin_amdgcn_mfma_f32_16x16x32_bf16(
                    af[mi], bf[ni], acc[mi][ni], 0, 0, 0);
        __syncthreads();
    }
    #pragma unroll
    for (int mi = 0; mi < 4; ++mi)
        #pragma unroll
        for (int ni = 0; ni < 2; ++ni)
            #pragma unroll
            for (int r = 0; r < 4; ++r) {
                int row = m0 + wr + mi * 16 + quad * 4 + r;
                int col = n0 + wc + ni * 16 + l16;
                C[(size_t)row * N + col] = acc[mi][ni][r];
            }
}

// ---------------------------------------------------------------------------
// Dual-score causal flash attention (attn7 structure, 32 KiB LDS, 5 blk/CU).
// Round-6: CU-BALANCED qt map. 1024 blocks are ALL co-resident at t=0
// (1024 < 5*256), so runtime = max per-CU work sum. Round-robin assignment
// gives CU group y0 the blocks y = y0+8t (t=0..3); old map qt=31-y summed to
// 80-4*y0 (range 52..80, mean 66). New bijection qt(y0,t) = {31-y0, 16+y0,
// 15-y0, y0} makes every CU sum exactly 66 -> ~17% critical-path cut.
// ---------------------------------------------------------------------------
__global__ __launch_bounds__(256, 5) void attn7(
    const unsigned short* __restrict__ qk, const float* __restrict__ qg,
    const unsigned short* __restrict__ kgb, const unsigned short* __restrict__ vt,
    unsigned short* __restrict__ y)
{
    const int L = 2048, DS = 2048, Dm = 1024;
    const float SC2 = 0.125f * 1.44269504088896f / 7.6246189861593985f;

    const int yb = (int)blockIdx.y;
    const int y0 = yb & 7, tq = yb >> 3;
    const int qt = (tq == 0) ? 31 - y0 : (tq == 1) ? 16 + y0
                 : (tq == 2) ? 15 - y0 : y0;     // bijective, per-CU sum = const
    const int bh = blockIdx.x, b = bh >> 4, h = bh & 15;
    const int tid = threadIdx.x, wave = tid >> 6, lane = tid & 63;
    const int quad = lane >> 4, l16 = lane & 15;

    __shared__ unsigned short K_l[4096];     // [64][64] swizzled
    __shared__ unsigned short G_l[4096];
    __shared__ unsigned short V_l[4096];     // [hd][key] swizzled
    __shared__ unsigned short P_l[4096];     // per-wave [16][64] swizzled
    unsigned short* Pw = &P_l[wave * 1024];

    bf16x8 qf[2], gf[2];
    {
        const int qrow = qt * 64 + wave * 16 + l16;
        const unsigned short* qp = qk + (size_t)(b * L + qrow) * DS + h * 64;
        const float* gp = qg + (size_t)(b * L + qrow) * Dm + h * 64;
        #pragma unroll
        for (int c = 0; c < 2; ++c) {
            qf[c] = scale8v(*(const bf16x8*)(qp + c * 32 + quad * 8), SC2);
            gf[c] = scale8v(cvt8v(gp + c * 32 + quad * 8), SC2);
        }
    }

    f32x4 o[4];
    #pragma unroll
    for (int nd = 0; nd < 4; ++nd) o[nd] = (f32x4){0.f, 0.f, 0.f, 0.f};
    float lsum = 0.f;

    const int srow = wave * 16 + (lane >> 3);
    const int c8 = (((lane & 7) ^ (lane >> 3)) & 7) * 8;
    const unsigned short* pk = qk + (size_t)(b * L + srow) * DS + 1024 + h * 64 + c8;
    const unsigned short* pg = kgb + (size_t)(b * L + srow) * Dm + h * 64 + c8;
    const unsigned short* pv = vt + ((size_t)bh * 64 + srow) * L + c8;
    unsigned short* lK = &K_l[wave * 1024];
    unsigned short* lG = &G_l[wave * 1024];
    unsigned short* lV = &V_l[wave * 1024];

    const int rb = l16 * 128;
    const int swz0 = ((quad     ^ (l16 & 7)) * 16);
    const int swz1 = (((4 + quad) ^ (l16 & 7)) * 16);
    // P write: short idx l16*64 + ((ni*2+(quad>>1))^(l16&7))*8 + (quad&1)*4
    const int pwb = l16 * 64 + (quad & 1) * 4;
    const int pwc = quad >> 1, pxr = l16 & 7;

    for (int kt = 0; kt < qt; ++kt) {
        __syncthreads();
        glds16(pk, lK); glds16(pk + 8 * DS, lK + 512);
        glds16(pg, lG); glds16(pg + 8 * Dm, lG + 512);
        glds16(pv, lV); glds16(pv + 8 * L,  lV + 512);
        pk += 64 * DS; pg += 64 * Dm; pv += 64;
        __syncthreads();

        #pragma unroll
        for (int ni = 0; ni < 4; ++ni) {
            bf16x8 kf0 = *(const bf16x8*)((const char*)K_l + rb + swz0 + ni * 2048);
            bf16x8 kf1 = *(const bf16x8*)((const char*)K_l + rb + swz1 + ni * 2048);
            bf16x8 gb0 = *(const bf16x8*)((const char*)G_l + rb + swz0 + ni * 2048);
            bf16x8 gb1 = *(const bf16x8*)((const char*)G_l + rb + swz1 + ni * 2048);
            f32x4 a = (f32x4){0.f, 0.f, 0.f, 0.f};
            a = __builtin_amdgcn_mfma_f32_16x16x32_bf16(kf0, qf[0], a, 0, 0, 0);
            a = __builtin_amdgcn_mfma_f32_16x16x32_bf16(gb0, gf[0], a, 0, 0, 0);
            a = __builtin_amdgcn_mfma_f32_16x16x32_bf16(kf1, qf[1], a, 0, 0, 0);
            a = __builtin_amdgcn_mfma_f32_16x16x32_bf16(gb1, gf[1], a, 0, 0, 0);
            float e0 = exp2f(a[0]), e1 = exp2f(a[1]);
            float e2 = exp2f(a[2]), e3 = exp2f(a[3]);
            lsum += (e0 + e1) + (e2 + e3);
            unsigned int p01 = pack2bf(e0, e1), p23 = pack2bf(e2, e3);
            *(unsigned long long*)&Pw[pwb + (((ni * 2 + pwc) ^ pxr) * 8)] =
                ((unsigned long long)p23 << 32) | p01;
        }
        asm volatile("s_waitcnt lgkmcnt(0)" ::: "memory");

        bf16x8 pa[2];
        #pragma unroll
        for (int c = 0; c < 2; ++c)
            pa[c] = *(const bf16x8*)&Pw[l16 * 64 + (((c * 4 + quad) ^ pxr) * 8)];
        #pragma unroll
        for (int nd = 0; nd < 4; ++nd) {
            bf16x8 vf0 = *(const bf16x8*)((const char*)V_l + rb + swz0 + nd * 2048);
            bf16x8 vf1 = *(const bf16x8*)((const char*)V_l + rb + swz1 + nd * 2048);
            o[nd] = __builtin_amdgcn_mfma_f32_16x16x32_bf16(pa[0], vf0, o[nd], 0, 0, 0);
            o[nd] = __builtin_amdgcn_mfma_f32_16x16x32_bf16(pa[1], vf1, o[nd], 0, 0, 0);
        }
    }

    // ---- diagonal tile kt == qt ----
    {
        __syncthreads();
        glds16(pk, lK); glds16(pk + 8 * DS, lK + 512);
        glds16(pg, lG); glds16(pg + 8 * Dm, lG + 512);
        glds16(pv, lV); glds16(pv + 8 * L,  lV + 512);
        __syncthreads();

        #pragma unroll
        for (int ni = 0; ni < 4; ++ni) {
            if (ni > wave) {
                *(unsigned long long*)&Pw[pwb + (((ni * 2 + pwc) ^ pxr) * 8)] = 0ull;
                continue;
            }
            bf16x8 kf0 = *(const bf16x8*)((const char*)K_l + rb + swz0 + ni * 2048);
            bf16x8 kf1 = *(const bf16x8*)((const char*)K_l + rb + swz1 + ni * 2048);
            bf16x8 gb0 = *(const bf16x8*)((const char*)G_l + rb + swz0 + ni * 2048);
            bf16x8 gb1 = *(const bf16x8*)((const char*)G_l + rb + swz1 + ni * 2048);
            f32x4 a = (f32x4){0.f, 0.f, 0.f, 0.f};
            a = __builtin_amdgcn_mfma_f32_16x16x32_bf16(kf0, qf[0], a, 0, 0, 0);
            a = __builtin_amdgcn_mfma_f32_16x16x32_bf16(gb0, gf[0], a, 0, 0, 0);
            a = __builtin_amdgcn_mfma_f32_16x16x32_bf16(kf1, qf[1], a, 0, 0, 0);
            a = __builtin_amdgcn_mfma_f32_16x16x32_bf16(gb1, gf[1], a, 0, 0, 0);
            float e0, e1, e2, e3;
            if (ni < wave) {
                e0 = exp2f(a[0]); e1 = exp2f(a[1]);
                e2 = exp2f(a[2]); e3 = exp2f(a[3]);
            } else {
                e0 = (quad * 4 + 0 <= l16) ? exp2f(a[0]) : 0.f;
                e1 = (quad * 4 + 1 <= l16) ? exp2f(a[1]) : 0.f;
                e2 = (quad * 4 + 2 <= l16) ? exp2f(a[2]) : 0.f;
                e3 = (quad * 4 + 3 <= l16) ? exp2f(a[3]) : 0.f;
            }
            lsum += (e0 + e1) + (e2 + e3);
            unsigned int p01 = pack2bf(e0, e1), p23 = pack2bf(e2, e3);
            *(unsigned long long*)&Pw[pwb + (((ni * 2 + pwc) ^ pxr) * 8)] =
                ((unsigned long long)p23 << 32) | p01;
        }
        asm volatile("s_waitcnt lgkmcnt(0)" ::: "memory");

        bf16x8 pa[2];
        #pragma unroll
        for (int c = 0; c < 2; ++c)
            pa[c] = *(const bf16x8*)&Pw[l16 * 64 + (((c * 4 + quad) ^ pxr) * 8)];
        #pragma unroll
        for (int nd = 0; nd < 4; ++nd) {
            bf16x8 vf0 = *(const bf16x8*)((const char*)V_l + rb + swz0 + nd * 2048);
            bf16x8 vf1 = *(const bf16x8*)((const char*)V_l + rb + swz1 + nd * 2048);
            o[nd] = __builtin_amdgcn_mfma_f32_16x16x32_bf16(pa[0], vf0, o[nd], 0, 0, 0);
            o[nd] = __builtin_amdgcn_mfma_f32_16x16x32_bf16(pa[1], vf1, o[nd], 0, 0, 0);
        }
    }

    float rs = lsum;
    rs += __shfl_xor(rs, 16);
    rs += __shfl_xor(rs, 32);
    #pragma unroll
    for (int r = 0; r < 4; ++r) {
        float inv = 1.f / __shfl(rs, (lane & 48) | (quad * 4 + r));
        int row = qt * 64 + wave * 16 + quad * 4 + r;
        #pragma unroll
        for (int nd = 0; nd < 4; ++nd)
            y[(size_t)(b * L + row) * Dm + h * 64 + nd * 16 + l16] =
                f2bf(o[nd][r] * inv);
    }
}

// ---------------------------------------------------------------------------
extern "C" void kernel_launch(void* const* d_in, const int* in_sizes, int n_in,
                              void* d_out, int out_size, void* d_ws, size_t ws_size,
                              hipStream_t stream) {
    const float* x     = (const float*)d_in[0];
    const float* q_g   = (const float*)d_in[1];
    const float* k_g   = (const float*)d_in[2];
    const float* W_qkv = (const float*)d_in[3];
    const float* W_out = (const float*)d_in[4];
    float* out = (float*)d_out;
    unsigned short* ws = (unsigned short*)d_ws;

    unsigned short* qk_ws = ws;                  // [4096][2048]  Q|K
    unsigned short* y_ws  = ws + 8388608;        // [4096][1024]
    unsigned short* wtq   = ws + 12582912;       // [3072][1024]
    unsigned short* wto   = ws + 15728640;       // [1024][1024]
    unsigned short* kg_bf = ws + 16777216;       // [4096][1024]
    unsigned short* x_bf  = ws + 20971520;       // [4096][1024]
    unsigned short* vt_bf = ws + 25165824;       // [32][64][2048]

    dim3 blk(256);
    prep_all<<<5120, blk, 0, stream>>>(x, x_bf, k_g, kg_bf, W_qkv, wtq, W_out, wto);
    gemm_qkv<<<dim3(24, 32), blk, 0, stream>>>(x_bf, wtq, qk_ws, vt_bf);
    attn7<<<dim3(32, 32), blk, 0, stream>>>(qk_ws, q_g, kg_bf, vt_bf, y_ws);
    gemm_n64<<<dim3(16, 32), blk, 0, stream>>>(y_ws, wto, out);
}